// Round 1
// baseline (136.582 us; speedup 1.0000x reference)
//
#include <hip/hip_runtime.h>

// Problem constants (reference: H=384, WG=384, F=K=256)
#define HH 384
#define WW 384
#define FF 256
#define KK 256
// M = HH*WW = 147456 rows; 16-row stripes -> 9216 stripes; 512 blocks * 18 stripes

typedef __attribute__((ext_vector_type(8))) short bf16x8;  // 8 bf16 in 4 VGPRs
typedef __attribute__((ext_vector_type(4))) float f32x4;   // MFMA C/D frag

// float -> bf16 bits, round-to-nearest-even
__device__ inline short f2bf(float x) {
    unsigned u = __float_as_uint(x);
    unsigned r = u + 0x7FFFu + ((u >> 16) & 1u);
    return (short)(r >> 16);
}

// Kernel 1: y^T[f][k] = bf16( sum_j x[sx[k], sy[k], j] * W[j][f] )
// One block per station k; thread = output feature f.
__global__ __launch_bounds__(256) void station_kernel(
        const float* __restrict__ x, const float* __restrict__ W,
        const int* __restrict__ sx, const int* __restrict__ sy,
        short* __restrict__ yt) {
    __shared__ float xrow[FF];
    const int k = blockIdx.x;
    const int f = threadIdx.x;
    const long base = ((long)sx[k] * WW + (long)sy[k]) * FF;
    xrow[f] = x[base + f];
    __syncthreads();
    float acc = 0.f;
    #pragma unroll 8
    for (int j = 0; j < FF; ++j)
        acc += xrow[j] * W[j * FF + f];   // coalesced across f
    yt[f * KK + k] = f2bf(acc);           // transposed store (128 KB total)
}

// Kernel 2: out[m,f] = sum_k d[m,k] * y[k,f]
// 4 waves/block; wave owns a 64-col N slice, B-frags in registers.
// Per 16-row stripe: A-frags straight from global (each row = 128B contiguous
// across the wave's 4 lane-groups), cvt f32->bf16, 32 MFMAs, direct C store.
__global__ __launch_bounds__(256, 2) void gemm_kernel(
        const float* __restrict__ d, const short* __restrict__ yt,
        float* __restrict__ out) {
    const int lane = threadIdx.x & 63;
    const int wv   = threadIdx.x >> 6;   // 0..3: N-slice
    const int l15  = lane & 15;
    const int lg   = lane >> 4;          // 0..3: k-subgroup
    const int fbase = wv * 64;

    // B fragments: lane holds y[kf*32 + lg*8 + i][fbase + nf*16 + l15],
    // i.e. 8 consecutive k from row (fbase+nf*16+l15) of y^T. 16B loads.
    bf16x8 bfrag[8][4];
    #pragma unroll
    for (int kf = 0; kf < 8; ++kf)
        #pragma unroll
        for (int nf = 0; nf < 4; ++nf) {
            const int fr = fbase + nf * 16 + l15;
            bfrag[kf][nf] = *(const bf16x8*)(yt + fr * KK + kf * 32 + lg * 8);
        }

    const int s0 = blockIdx.x * 18;
    for (int s = s0; s < s0 + 18; ++s) {
        const int m0 = s * 16;
        // A: lane reads d[m0 + l15][kf*32 + lg*8 .. +7]
        const float* dp = d + (size_t)(m0 + l15) * KK + lg * 8;

        f32x4 acc[4];
        #pragma unroll
        for (int nf = 0; nf < 4; ++nf)
            #pragma unroll
            for (int r = 0; r < 4; ++r) acc[nf][r] = 0.f;

        #pragma unroll
        for (int kf = 0; kf < 8; ++kf) {
            float4 lo = *(const float4*)(dp + kf * 32);
            float4 hi = *(const float4*)(dp + kf * 32 + 4);
            bf16x8 a;
            a[0] = f2bf(lo.x); a[1] = f2bf(lo.y);
            a[2] = f2bf(lo.z); a[3] = f2bf(lo.w);
            a[4] = f2bf(hi.x); a[5] = f2bf(hi.y);
            a[6] = f2bf(hi.z); a[7] = f2bf(hi.w);
            #pragma unroll
            for (int nf = 0; nf < 4; ++nf)
                acc[nf] = __builtin_amdgcn_mfma_f32_16x16x32_bf16(
                              a, bfrag[kf][nf], acc[nf], 0, 0, 0);
        }

        // C store: row = m0 + lg*4 + r, col = fbase + nf*16 + l15 (m89 layout)
        float* ob = out + (size_t)m0 * FF + fbase;
        #pragma unroll
        for (int nf = 0; nf < 4; ++nf)
            #pragma unroll
            for (int r = 0; r < 4; ++r)
                ob[(size_t)(lg * 4 + r) * FF + nf * 16 + l15] = acc[nf][r];
    }
}

extern "C" void kernel_launch(void* const* d_in, const int* in_sizes, int n_in,
                              void* d_out, int out_size, void* d_ws, size_t ws_size,
                              hipStream_t stream) {
    const float* x  = (const float*)d_in[0];
    const float* d  = (const float*)d_in[1];
    const float* W  = (const float*)d_in[2];
    const int*   sx = (const int*)d_in[3];
    const int*   sy = (const int*)d_in[4];
    float* out = (float*)d_out;
    short* yt  = (short*)d_ws;  // 256*256*2 = 128 KB scratch

    station_kernel<<<dim3(KK), dim3(FF), 0, stream>>>(x, W, sx, sy, yt);
    gemm_kernel<<<dim3(512), dim3(256), 0, stream>>>(d, yt, out);
}

// Round 2
// 84.099 us; speedup vs baseline: 1.6241x; 1.6241x over previous
//
#include <hip/hip_runtime.h>

// Problem: H=W=384, F=K=256. M = 147456 rows.
// out[m,f] = sum_k d[m,k] * y[k,f],  y = x[stations] @ W  (256x256, tiny)
#define FF 256
#define KK 256
#define RR 32                 // rows per block in gemm kernel
#define NBLK 4608             // 147456 / 32

typedef __attribute__((ext_vector_type(8))) short bf16x8;   // 8 bf16 (4 VGPR)
typedef __attribute__((ext_vector_type(4))) float f32x4;    // MFMA C/D frag
typedef __attribute__((ext_vector_type(4))) short short4v;  // 4 bf16 (8 B)

// float -> bf16 bits, round-to-nearest-even
__device__ inline short f2bf(float x) {
    unsigned u = __float_as_uint(x);
    unsigned r = u + 0x7FFFu + ((u >> 16) & 1u);
    return (short)(r >> 16);
}

// Kernel 1: compute y[k][f] = sum_j x[sx[k],sy[k],j] * W[j][f], store bf16 in
// FRAGMENT ORDER so kernel-2 B loads are lane-contiguous:
//   idx(k,f) = ((f>>4)*8 + (k>>5))*512 + (((k>>3)&3)*16 + (f&15))*8 + (k&7)
// (g=f>>4 colgroup, kf=k>>5, lane=lg*16+l15 with lg=(k>>3)&3, l15=f&15, j=k&7)
__global__ __launch_bounds__(256) void station_kernel(
        const float* __restrict__ x, const float* __restrict__ W,
        const int* __restrict__ sx, const int* __restrict__ sy,
        short* __restrict__ yp) {
    __shared__ float xrow[FF];
    const int k = blockIdx.x;
    const int f = threadIdx.x;
    const long base = ((long)sx[k] * 384 + (long)sy[k]) * FF;
    xrow[f] = x[base + f];
    __syncthreads();
    float acc = 0.f;
    #pragma unroll 8
    for (int j = 0; j < FF; ++j)
        acc += xrow[j] * W[j * FF + f];   // coalesced across f
    const int idx = ((f >> 4) * 8 + (k >> 5)) * 512
                  + (((k >> 3) & 3) * 16 + (f & 15)) * 8 + (k & 7);
    yp[idx] = f2bf(acc);
}

// Kernel 2: one block per 32-row stripe. Stage d-stripe into LDS as bf16
// (coalesced float4 global reads, XOR-swizzled LDS), then 4 waves x 64-col
// slices, A-frags via ds_read_b128 (conflict-free), B-frags via coalesced
// 16B/lane loads of the packed y (L2-resident 128 KB).
__global__ __launch_bounds__(256, 4) void gemm_kernel(
        const float* __restrict__ d, const short* __restrict__ yp,
        float* __restrict__ out) {
    __shared__ __align__(16) short albs[RR * KK];   // 16 KB bf16, swizzled
    const int t    = threadIdx.x;
    const int lane = t & 63;
    const int wv   = t >> 6;          // 0..3: 64-col slice
    const int l15  = lane & 15;
    const int lg   = lane >> 4;       // 0..3: k-subgroup
    const long m0  = (long)blockIdx.x * RR;

    // ---- stage: 32 rows x 256 f32 -> bf16 LDS (swizzled) ----
    const float* dbase = d + m0 * KK;
    char* lb = (char*)albs;
    #pragma unroll
    for (int r = 0; r < 8; ++r) {
        const int e   = (r * 256 + t) * 4;    // float index in stripe
        const int row = e >> 8;               // 256 floats per row
        const int k0  = e & 255;
        float4 v = *(const float4*)(dbase + e);
        short4v b;
        b.x = f2bf(v.x); b.y = f2bf(v.y); b.z = f2bf(v.z); b.w = f2bf(v.w);
        int byte = row * 512 + k0 * 2;
        byte ^= (row & 7) << 4;               // bank swizzle (G4)
        *(short4v*)(lb + byte) = b;
    }
    __syncthreads();

    // ---- compute ----
    f32x4 acc[2][4];
    #pragma unroll
    for (int mt = 0; mt < 2; ++mt)
        #pragma unroll
        for (int nf = 0; nf < 4; ++nf)
            #pragma unroll
            for (int q = 0; q < 4; ++q) acc[mt][nf][q] = 0.f;

    #pragma unroll
    for (int kf = 0; kf < 8; ++kf) {
        const int cb = kf * 64 + lg * 16;     // col-byte within row
        const int r0 = l15;
        const int r1 = 16 + l15;
        bf16x8 a0 = *(const bf16x8*)(lb + ((r0 * 512 + cb) ^ ((r0 & 7) << 4)));
        bf16x8 a1 = *(const bf16x8*)(lb + ((r1 * 512 + cb) ^ ((r1 & 7) << 4)));
        #pragma unroll
        for (int nf = 0; nf < 4; ++nf) {
            const int g = wv * 4 + nf;
            bf16x8 bfrag = *(const bf16x8*)(yp + ((g * 8 + kf) << 9) + (lane << 3));
            acc[0][nf] = __builtin_amdgcn_mfma_f32_16x16x32_bf16(
                             a0, bfrag, acc[0][nf], 0, 0, 0);
            acc[1][nf] = __builtin_amdgcn_mfma_f32_16x16x32_bf16(
                             a1, bfrag, acc[1][nf], 0, 0, 0);
        }
    }

    // ---- store: row = mt*16 + lg*4 + q, col = wv*64 + nf*16 + l15 ----
    float* ob = out + m0 * FF + wv * 64;
    #pragma unroll
    for (int mt = 0; mt < 2; ++mt)
        #pragma unroll
        for (int nf = 0; nf < 4; ++nf)
            #pragma unroll
            for (int q = 0; q < 4; ++q)
                ob[(long)(mt * 16 + lg * 4 + q) * FF + nf * 16 + l15]
                    = acc[mt][nf][q];
}

extern "C" void kernel_launch(void* const* d_in, const int* in_sizes, int n_in,
                              void* d_out, int out_size, void* d_ws, size_t ws_size,
                              hipStream_t stream) {
    const float* x  = (const float*)d_in[0];
    const float* d  = (const float*)d_in[1];
    const float* W  = (const float*)d_in[2];
    const int*   sx = (const int*)d_in[3];
    const int*   sy = (const int*)d_in[4];
    float* out = (float*)d_out;
    short* yp  = (short*)d_ws;   // 256*256 bf16 = 128 KB packed fragment buffer

    station_kernel<<<dim3(KK), dim3(FF), 0, stream>>>(x, W, sx, sy, yp);
    gemm_kernel<<<dim3(NBLK), dim3(256), 0, stream>>>(d, yp, out);
}